// Round 4
// baseline (398.042 us; speedup 1.0000x reference)
//
#include <hip/hip_runtime.h>

#define N_NODES 100000
#define N_EDGES 1250000
#define D 64
#define ED 32
#define SCAN_BS 512
#define SCAN_NB 196   // ceil(100000/512)

// ---------------- CSR build ----------------

__global__ void __launch_bounds__(256) hist_k(const int* __restrict__ col,
                                              int* __restrict__ cnt) {
    int i = blockIdx.x * blockDim.x + threadIdx.x;
    int stride = gridDim.x * blockDim.x;
    const int4* c4 = (const int4*)col;
    for (int j = i; j < N_EDGES / 4; j += stride) {
        int4 c = c4[j];
        atomicAdd(&cnt[c.x], 1); atomicAdd(&cnt[c.y], 1);
        atomicAdd(&cnt[c.z], 1); atomicAdd(&cnt[c.w], 1);
    }
}

__global__ void __launch_bounds__(SCAN_BS) scan_local_k(const int* __restrict__ cnt,
                                                        int* __restrict__ base,
                                                        int* __restrict__ bsum) {
    __shared__ int s[SCAN_BS];
    const int t = threadIdx.x;
    const int i = blockIdx.x * SCAN_BS + t;
    const int v = (i < N_NODES) ? cnt[i] : 0;
    s[t] = v;
    __syncthreads();
    for (int off = 1; off < SCAN_BS; off <<= 1) {
        int tv = (t >= off) ? s[t - off] : 0;
        __syncthreads();
        s[t] += tv;
        __syncthreads();
    }
    if (i < N_NODES) base[i] = s[t] - v;
    if (t == SCAN_BS - 1) bsum[blockIdx.x] = s[t];
}

__global__ void __launch_bounds__(256) scan_bsum_k(const int* __restrict__ bsum,
                                                   int* __restrict__ boff) {
    __shared__ int s[256];
    const int t = threadIdx.x;
    const int v = (t < SCAN_NB) ? bsum[t] : 0;
    s[t] = v;
    __syncthreads();
    for (int off = 1; off < 256; off <<= 1) {
        int tv = (t >= off) ? s[t - off] : 0;
        __syncthreads();
        s[t] += tv;
        __syncthreads();
    }
    if (t < SCAN_NB) boff[t] = s[t] - v;
}

__global__ void __launch_bounds__(SCAN_BS) scan_add_k(int* __restrict__ base,
                                                      const int* __restrict__ boff,
                                                      int* __restrict__ cursor) {
    const int i = blockIdx.x * SCAN_BS + threadIdx.x;
    if (i < N_NODES) {
        const int b = base[i] + boff[blockIdx.x];
        base[i] = b;
        cursor[i] = b;
    }
    if (i == 0) base[N_NODES] = N_EDGES;
}

// scatter int2{row[e], e}: removes one indirection level from agg_k's chain
__global__ void __launch_bounds__(256) scatter_k(const int* __restrict__ row,
                                                 const int* __restrict__ col,
                                                 int* __restrict__ cursor,
                                                 int2* __restrict__ erec) {
    int i = blockIdx.x * blockDim.x + threadIdx.x;
    int stride = gridDim.x * blockDim.x;
    for (int e = i; e < N_EDGES; e += stride) {
        const int c = col[e];
        const int r = row[e];                 // coalesced here
        const int pos = atomicAdd(&cursor[c], 1);
        erec[pos] = make_int2(r, e);
    }
}

// ---------------- aggregation: z = segsum(x[row]) + segsum(ea)@ew^T + deg*eb ----------------
// Wave per node (grid-stride). Lanes 0..deg-1 load edge records in parallel,
// shfl-broadcast, so all gathers for a node are independent in-flight loads.

__global__ void __launch_bounds__(256) agg_k(const float* __restrict__ x,
                                             const float* __restrict__ ea,
                                             const int* __restrict__ base,
                                             const int2* __restrict__ erec,
                                             const float* __restrict__ ew,
                                             const float* __restrict__ eb,
                                             float* __restrict__ z) {     // = d_out [N][64]
    const int lane = threadIdx.x & 63;
    const int wid  = blockIdx.x * (blockDim.x >> 6) + (threadIdx.x >> 6);
    const int nw   = gridDim.x * (blockDim.x >> 6);

    // lane d holds ew[d][0..31] (float4 loads: 4x fewer line-touches)
    float w[ED];
    const float4* ew4 = (const float4*)(ew + (size_t)lane * ED);
#pragma unroll
    for (int q = 0; q < ED / 4; ++q) {
        const float4 v = ew4[q];
        w[4*q+0] = v.x; w[4*q+1] = v.y; w[4*q+2] = v.z; w[4*q+3] = v.w;
    }
    const float ebl = eb[lane];

    for (int n = wid; n < N_NODES; n += nw) {
        const int j0 = base[n], j1 = base[n + 1];
        float ax0 = 0.f, ax1 = 0.f, a32 = 0.f;

        for (int jb = j0; jb < j1; jb += 64) {
            const int cnt = min(64, j1 - jb);           // wave-uniform
            int2 rec = make_int2(0, -1);
            if (lane < cnt) rec = erec[jb + lane];      // one coalesced 8B load

            // x gathers: all independent, 2 accumulator chains
            int k = 0;
            for (; k + 1 < cnt; k += 2) {
                const int r0 = __shfl(rec.x, k);
                const int r1 = __shfl(rec.x, k + 1);
                ax0 += x[(size_t)r0 * D + lane];
                ax1 += x[(size_t)r1 * D + lane];
            }
            if (k < cnt) ax0 += x[(size_t)__shfl(rec.x, k) * D + lane];

            // ea gathers: half-wave per edge (2 rows / instruction)
            for (k = 0; k < cnt; k += 2) {
                const int e0 = __shfl(rec.y, k);
                const int e1 = (k + 1 < cnt) ? __shfl(rec.y, k + 1) : -1;
                const int ee = (lane < 32) ? e0 : e1;
                if (ee >= 0) a32 += ea[(size_t)ee * ED + (lane & 31)];
            }
        }

        a32 += __shfl_xor(a32, 32);          // lane j (j<32) now holds agg32[n][j]

        float zd = ax0 + ax1;
#pragma unroll
        for (int j = 0; j < ED; ++j)
            zd = fmaf(__shfl(a32, j), w[j], zd);
        zd = fmaf((float)(j1 - j0), ebl, zd);           // + deg*eb
        z[(size_t)n * D + lane] = zd;
    }
}

// ---------------- epilogue: out = inv * z@lw^T + lb ----------------

__global__ void __launch_bounds__(256) out_k(float* __restrict__ z,   // in/out = d_out
                                             const int* __restrict__ base,
                                             const float* __restrict__ lw,
                                             const float* __restrict__ lb) {
    const int lane = threadIdx.x & 63;
    const int wid  = blockIdx.x * (blockDim.x >> 6) + (threadIdx.x >> 6);
    const int nw   = gridDim.x * (blockDim.x >> 6);

    float w[D];
    const float4* lw4 = (const float4*)(lw + (size_t)lane * D);
#pragma unroll
    for (int q = 0; q < D / 4; ++q) {
        const float4 v = lw4[q];
        w[4*q+0] = v.x; w[4*q+1] = v.y; w[4*q+2] = v.z; w[4*q+3] = v.w;
    }
    const float bias = lb[lane];

    for (int n = wid; n < N_NODES; n += nw) {
        const int dg = base[n + 1] - base[n];
        const float inv = 1.f / fmaxf((float)dg, 1.f);
        const float4* zz = (const float4*)(z + (size_t)n * D);
        float d0 = 0.f, d1 = 0.f;
#pragma unroll
        for (int q = 0; q < D / 8; ++q) {
            const float4 v0 = zz[q];
            const float4 v1 = zz[q + 8];
            d0 = fmaf(v0.x, w[4*q+0], d0);  d0 = fmaf(v0.y, w[4*q+1], d0);
            d0 = fmaf(v0.z, w[4*q+2], d0);  d0 = fmaf(v0.w, w[4*q+3], d0);
            d1 = fmaf(v1.x, w[4*q+32], d1); d1 = fmaf(v1.y, w[4*q+33], d1);
            d1 = fmaf(v1.z, w[4*q+34], d1); d1 = fmaf(v1.w, w[4*q+35], d1);
        }
        z[(size_t)n * D + lane] = fmaf(inv, d0 + d1, bias);
    }
}

// ---------------- fallback (small ws): atomic version ----------------

__global__ void __launch_bounds__(256) edge_scatter_fb(
    const float* __restrict__ x, const int* __restrict__ ei,
    const float* __restrict__ ea, const float* __restrict__ ew,
    const float* __restrict__ eb, float* __restrict__ agg, float* __restrict__ deg) {
    const int lane = threadIdx.x & 63;
    const int wid  = blockIdx.x * (blockDim.x >> 6) + (threadIdx.x >> 6);
    const int nw   = gridDim.x * (blockDim.x >> 6);
    float w[ED];
#pragma unroll
    for (int k = 0; k < ED; ++k) w[k] = ew[lane * ED + k];
    const float b = eb[lane];
    for (int e = wid; e < N_EDGES; e += nw) {
        const int r = ei[e];
        const int c = ei[N_EDGES + e];
        const float4* ea4 = (const float4*)(ea + (size_t)e * ED);
        float acc = b;
#pragma unroll
        for (int q = 0; q < ED / 4; ++q) {
            float4 v = ea4[q];
            acc = fmaf(v.x, w[4*q+0], acc); acc = fmaf(v.y, w[4*q+1], acc);
            acc = fmaf(v.z, w[4*q+2], acc); acc = fmaf(v.w, w[4*q+3], acc);
        }
        acc += x[(size_t)r * D + lane];
        atomicAdd(&agg[(size_t)c * D + lane], acc);
        if (lane == 0) atomicAdd(&deg[c], 1.0f);
    }
}

__global__ void __launch_bounds__(256) node_linear_fb(
    float* __restrict__ agg, const float* __restrict__ deg,
    const float* __restrict__ lw, const float* __restrict__ lb) {
    const int lane = threadIdx.x & 63;
    const int wid  = blockIdx.x * (blockDim.x >> 6) + (threadIdx.x >> 6);
    const int nw   = gridDim.x * (blockDim.x >> 6);
    float w[D];
#pragma unroll
    for (int k = 0; k < D; ++k) w[k] = lw[lane * D + k];
    const float b = lb[lane];
    for (int n = wid; n < N_NODES; n += nw) {
        const float inv = 1.0f / fmaxf(deg[n], 1.0f);
        const float4* a4 = (const float4*)(agg + (size_t)n * D);
        float dot = 0.0f;
#pragma unroll
        for (int q = 0; q < D / 4; ++q) {
            float4 v = a4[q];
            dot = fmaf(v.x, w[4*q+0], dot); dot = fmaf(v.y, w[4*q+1], dot);
            dot = fmaf(v.z, w[4*q+2], dot); dot = fmaf(v.w, w[4*q+3], dot);
        }
        agg[(size_t)n * D + lane] = fmaf(inv, dot, b);
    }
}

// ---------------- launch ----------------

extern "C" void kernel_launch(void* const* d_in, const int* in_sizes, int n_in,
                              void* d_out, int out_size, void* d_ws, size_t ws_size,
                              hipStream_t stream) {
    const float* x  = (const float*)d_in[0];
    const int*   ei = (const int*)d_in[1];     // [2][E]: rows then cols
    const float* ea = (const float*)d_in[2];
    const float* lw = (const float*)d_in[3];
    const float* lb = (const float*)d_in[4];
    const float* ew = (const float*)d_in[5];
    const float* eb = (const float*)d_in[6];
    const int* row = ei;
    const int* col = ei + N_EDGES;

    // ws layout (bytes, 16-aligned)
    const size_t OFF_EREC = 0;                 // E int2   = 10,000,000
    const size_t OFF_CNT  = 10000000;          // N ints   =    400,000 (doubles as cursor)
    const size_t OFF_BASE = 10400000;          // N+1 ints =    400,016 (padded)
    const size_t OFF_BSUM = 10800016;          // 196 ints
    const size_t OFF_BOFF = 10800800;          // 196 ints
    const size_t REQUIRED = 10801584;

    char* ws = (char*)d_ws;
    float* zout = (float*)d_out;

    if (ws_size >= REQUIRED) {
        int2* erec = (int2*)(ws + OFF_EREC);
        int*  cnt  = (int*)(ws + OFF_CNT);
        int*  base = (int*)(ws + OFF_BASE);
        int*  bsum = (int*)(ws + OFF_BSUM);
        int*  boff = (int*)(ws + OFF_BOFF);

        hipMemsetAsync(cnt, 0, (size_t)N_NODES * sizeof(int), stream);
        hist_k      <<<1024, 256, 0, stream>>>(col, cnt);
        scan_local_k<<<SCAN_NB, SCAN_BS, 0, stream>>>(cnt, base, bsum);
        scan_bsum_k <<<1, 256, 0, stream>>>(bsum, boff);
        scan_add_k  <<<SCAN_NB, SCAN_BS, 0, stream>>>(base, boff, cnt /*cursor*/);
        scatter_k   <<<1024, 256, 0, stream>>>(row, col, cnt /*cursor*/, erec);
        agg_k       <<<2048, 256, 0, stream>>>(x, ea, base, erec, ew, eb, zout);
        out_k       <<<1024, 256, 0, stream>>>(zout, base, lw, lb);
    } else {
        float* deg = (float*)d_ws;
        hipMemsetAsync(zout, 0, (size_t)N_NODES * D * sizeof(float), stream);
        hipMemsetAsync(deg, 0, (size_t)N_NODES * sizeof(float), stream);
        edge_scatter_fb<<<2048, 256, 0, stream>>>(x, ei, ea, ew, eb, zout, deg);
        node_linear_fb <<<1024, 256, 0, stream>>>(zout, deg, lw, lb);
    }
}

// Round 5
// 355.473 us; speedup vs baseline: 1.1198x; 1.1198x over previous
//
#include <hip/hip_runtime.h>

#define N_NODES 100000
#define N_EDGES 1250000
#define D 64
#define ED 32
#define SCAN_BS 512
#define SCAN_NB 196   // ceil(100000/512)

typedef unsigned int uint;
typedef unsigned short ushort;

// bf16 round-to-nearest-even helpers
__device__ __forceinline__ uint bfr(float f) {
    uint u = __float_as_uint(f);
    return (u + 0x7FFFu + ((u >> 16) & 1u)) >> 16;
}
__device__ __forceinline__ uint pk(float a, float b) { return bfr(a) | (bfr(b) << 16); }
__device__ __forceinline__ float bfu(ushort s) { return __uint_as_float(((uint)s) << 16); }

// ---------------- CSR build ----------------

__global__ void __launch_bounds__(256) hist_k(const int* __restrict__ col,
                                              int* __restrict__ cnt) {
    int i = blockIdx.x * blockDim.x + threadIdx.x;
    int stride = gridDim.x * blockDim.x;
    const int4* c4 = (const int4*)col;
    for (int j = i; j < N_EDGES / 4; j += stride) {
        int4 c = c4[j];
        atomicAdd(&cnt[c.x], 1); atomicAdd(&cnt[c.y], 1);
        atomicAdd(&cnt[c.z], 1); atomicAdd(&cnt[c.w], 1);
    }
}

__global__ void __launch_bounds__(SCAN_BS) scan_local_k(const int* __restrict__ cnt,
                                                        int* __restrict__ base,
                                                        int* __restrict__ bsum) {
    __shared__ int s[SCAN_BS];
    const int t = threadIdx.x;
    const int i = blockIdx.x * SCAN_BS + t;
    const int v = (i < N_NODES) ? cnt[i] : 0;
    s[t] = v;
    __syncthreads();
    for (int off = 1; off < SCAN_BS; off <<= 1) {
        int tv = (t >= off) ? s[t - off] : 0;
        __syncthreads();
        s[t] += tv;
        __syncthreads();
    }
    if (i < N_NODES) base[i] = s[t] - v;
    if (t == SCAN_BS - 1) bsum[blockIdx.x] = s[t];
}

__global__ void __launch_bounds__(256) scan_bsum_k(const int* __restrict__ bsum,
                                                   int* __restrict__ boff) {
    __shared__ int s[256];
    const int t = threadIdx.x;
    const int v = (t < SCAN_NB) ? bsum[t] : 0;
    s[t] = v;
    __syncthreads();
    for (int off = 1; off < 256; off <<= 1) {
        int tv = (t >= off) ? s[t - off] : 0;
        __syncthreads();
        s[t] += tv;
        __syncthreads();
    }
    if (t < SCAN_NB) boff[t] = s[t] - v;
}

__global__ void __launch_bounds__(SCAN_BS) scan_add_k(int* __restrict__ base,
                                                      const int* __restrict__ boff,
                                                      int* __restrict__ cursor) {
    const int i = blockIdx.x * SCAN_BS + threadIdx.x;
    if (i < N_NODES) {
        const int b = base[i] + boff[blockIdx.x];
        base[i] = b;
        cursor[i] = b;
    }
    if (i == 0) base[N_NODES] = N_EDGES;
}

// ---------------- payload permute: eap[pos] = bf16(ea[e]), rowp[pos] = row[e] ----------------
// Random writes are fire-and-forget; reads are coalesced/streamed.

__global__ void __launch_bounds__(256) scatter_perm_k(const int* __restrict__ row,
                                                      const int* __restrict__ col,
                                                      int* __restrict__ cursor,
                                                      const float* __restrict__ ea,
                                                      int* __restrict__ rowp,
                                                      ushort* __restrict__ eap) {
    int i = blockIdx.x * blockDim.x + threadIdx.x;
    int stride = gridDim.x * blockDim.x;
    for (int e = i; e < N_EDGES; e += stride) {
        const int c = col[e];
        const int r = row[e];
        const int pos = atomicAdd(&cursor[c], 1);
        rowp[pos] = r;
        const float4* src = (const float4*)(ea + (size_t)e * ED);
        uint4 o[4];
#pragma unroll
        for (int q = 0; q < 4; ++q) {
            const float4 va = src[2 * q];
            const float4 vb = src[2 * q + 1];
            o[q].x = pk(va.x, va.y); o[q].y = pk(va.z, va.w);
            o[q].z = pk(vb.x, vb.y); o[q].w = pk(vb.z, vb.w);
        }
        uint4* dst = (uint4*)(eap + (size_t)pos * ED);
        dst[0] = o[0]; dst[1] = o[1]; dst[2] = o[2]; dst[3] = o[3];
    }
}

// ---------------- aggregation (streamed payload): z = segsum(x[row]) + segsum(ea)@ew^T + deg*eb
// Wave per contiguous node range -> rowp/eap reads are sequential across the grid.

__global__ void __launch_bounds__(256) agg_k(const float* __restrict__ x,
                                             const int* __restrict__ base,
                                             const int* __restrict__ rowp,
                                             const ushort* __restrict__ eap,
                                             const float* __restrict__ ew,
                                             const float* __restrict__ eb,
                                             float* __restrict__ z) {     // = d_out
    const int lane = threadIdx.x & 63;
    const int wid  = blockIdx.x * (blockDim.x >> 6) + (threadIdx.x >> 6);
    const int nw   = gridDim.x * (blockDim.x >> 6);

    float w[ED];
    const float4* ew4 = (const float4*)(ew + (size_t)lane * ED);
#pragma unroll
    for (int q = 0; q < ED / 4; ++q) {
        const float4 v = ew4[q];
        w[4*q+0] = v.x; w[4*q+1] = v.y; w[4*q+2] = v.z; w[4*q+3] = v.w;
    }
    const float ebl = eb[lane];

    const int npw = (N_NODES + nw - 1) / nw;      // nodes per wave (contiguous)
    const int n0 = wid * npw;
    const int n1 = min(n0 + npw, N_NODES);

    for (int n = n0; n < n1; ++n) {
        const int j0 = base[n], j1 = base[n + 1];
        float ax0 = 0.f, ax1 = 0.f, ax2 = 0.f, ax3 = 0.f;
        float a0 = 0.f, a1 = 0.f, a2 = 0.f, a3 = 0.f;

        for (int jb = j0; jb < j1; jb += 64) {
            const int cnt = min(64, j1 - jb);
            int r = 0;
            if (lane < cnt) r = rowp[jb + lane];      // coalesced

            // x gathers: 4 independent chains (MLP)
            int k = 0;
            for (; k + 3 < cnt; k += 4) {
                const int r0 = __shfl(r, k),     r1 = __shfl(r, k + 1);
                const int r2 = __shfl(r, k + 2), r3 = __shfl(r, k + 3);
                ax0 += x[(size_t)r0 * D + lane];
                ax1 += x[(size_t)r1 * D + lane];
                ax2 += x[(size_t)r2 * D + lane];
                ax3 += x[(size_t)r3 * D + lane];
            }
            for (; k < cnt; ++k) ax0 += x[(size_t)__shfl(r, k) * D + lane];

            // ea payload: sequential bf16 stream, 2 edges per 128B load, 4 chains
            const ushort* ep = eap + (size_t)jb * ED + lane;  // lane<32: edge t0 dim lane; lane>=32: edge t0+1 dim lane-32
            const int npair = cnt >> 1;
            int t = 0;
            for (; t + 3 < npair; t += 4) {
                a0 += bfu(ep[(t + 0) * 64]);
                a1 += bfu(ep[(t + 1) * 64]);
                a2 += bfu(ep[(t + 2) * 64]);
                a3 += bfu(ep[(t + 3) * 64]);
            }
            for (; t < npair; ++t) a0 += bfu(ep[t * 64]);
            if (cnt & 1) {                              // odd tail edge: lanes<32 only
                if (lane < 32) a0 += bfu(eap[(size_t)(jb + cnt - 1) * ED + lane]);
            }
        }

        float a32 = (a0 + a1) + (a2 + a3);
        a32 += __shfl_xor(a32, 32);      // lane j now holds full segsum(ea)[n][j%32]

        float zd = (ax0 + ax1) + (ax2 + ax3);
#pragma unroll
        for (int j = 0; j < ED; ++j)
            zd = fmaf(__shfl(a32, j), w[j], zd);
        zd = fmaf((float)(j1 - j0), ebl, zd);           // + deg*eb
        z[(size_t)n * D + lane] = zd;
    }
}

// ---------------- epilogue: out = inv * z@lw^T + lb ----------------

__global__ void __launch_bounds__(256) out_k(float* __restrict__ z,   // in/out = d_out
                                             const int* __restrict__ base,
                                             const float* __restrict__ lw,
                                             const float* __restrict__ lb) {
    const int lane = threadIdx.x & 63;
    const int wid  = blockIdx.x * (blockDim.x >> 6) + (threadIdx.x >> 6);
    const int nw   = gridDim.x * (blockDim.x >> 6);

    float w[D];
    const float4* lw4 = (const float4*)(lw + (size_t)lane * D);
#pragma unroll
    for (int q = 0; q < D / 4; ++q) {
        const float4 v = lw4[q];
        w[4*q+0] = v.x; w[4*q+1] = v.y; w[4*q+2] = v.z; w[4*q+3] = v.w;
    }
    const float bias = lb[lane];

    for (int n = wid; n < N_NODES; n += nw) {
        const int dg = base[n + 1] - base[n];
        const float inv = 1.f / fmaxf((float)dg, 1.f);
        const float4* zz = (const float4*)(z + (size_t)n * D);
        float d0 = 0.f, d1 = 0.f;
#pragma unroll
        for (int q = 0; q < D / 8; ++q) {
            const float4 v0 = zz[q];
            const float4 v1 = zz[q + 8];
            d0 = fmaf(v0.x, w[4*q+0], d0);  d0 = fmaf(v0.y, w[4*q+1], d0);
            d0 = fmaf(v0.z, w[4*q+2], d0);  d0 = fmaf(v0.w, w[4*q+3], d0);
            d1 = fmaf(v1.x, w[4*q+32], d1); d1 = fmaf(v1.y, w[4*q+33], d1);
            d1 = fmaf(v1.z, w[4*q+34], d1); d1 = fmaf(v1.w, w[4*q+35], d1);
        }
        z[(size_t)n * D + lane] = fmaf(inv, d0 + d1, bias);
    }
}

// ---------------- fallback B (ws >= 10.8MB): R4 pipeline ----------------

__global__ void __launch_bounds__(256) scatter_fb_k(const int* __restrict__ row,
                                                    const int* __restrict__ col,
                                                    int* __restrict__ cursor,
                                                    int2* __restrict__ erec) {
    int i = blockIdx.x * blockDim.x + threadIdx.x;
    int stride = gridDim.x * blockDim.x;
    for (int e = i; e < N_EDGES; e += stride) {
        const int c = col[e];
        const int r = row[e];
        const int pos = atomicAdd(&cursor[c], 1);
        erec[pos] = make_int2(r, e);
    }
}

__global__ void __launch_bounds__(256) agg_fb_k(const float* __restrict__ x,
                                                const float* __restrict__ ea,
                                                const int* __restrict__ base,
                                                const int2* __restrict__ erec,
                                                const float* __restrict__ ew,
                                                const float* __restrict__ eb,
                                                float* __restrict__ z) {
    const int lane = threadIdx.x & 63;
    const int wid  = blockIdx.x * (blockDim.x >> 6) + (threadIdx.x >> 6);
    const int nw   = gridDim.x * (blockDim.x >> 6);
    float w[ED];
    const float4* ew4 = (const float4*)(ew + (size_t)lane * ED);
#pragma unroll
    for (int q = 0; q < ED / 4; ++q) {
        const float4 v = ew4[q];
        w[4*q+0] = v.x; w[4*q+1] = v.y; w[4*q+2] = v.z; w[4*q+3] = v.w;
    }
    const float ebl = eb[lane];
    for (int n = wid; n < N_NODES; n += nw) {
        const int j0 = base[n], j1 = base[n + 1];
        float ax0 = 0.f, ax1 = 0.f, a32 = 0.f;
        for (int jb = j0; jb < j1; jb += 64) {
            const int cnt = min(64, j1 - jb);
            int2 rec = make_int2(0, -1);
            if (lane < cnt) rec = erec[jb + lane];
            int k = 0;
            for (; k + 1 < cnt; k += 2) {
                const int r0 = __shfl(rec.x, k);
                const int r1 = __shfl(rec.x, k + 1);
                ax0 += x[(size_t)r0 * D + lane];
                ax1 += x[(size_t)r1 * D + lane];
            }
            if (k < cnt) ax0 += x[(size_t)__shfl(rec.x, k) * D + lane];
            for (k = 0; k < cnt; k += 2) {
                const int e0 = __shfl(rec.y, k);
                const int e1 = (k + 1 < cnt) ? __shfl(rec.y, k + 1) : -1;
                const int ee = (lane < 32) ? e0 : e1;
                if (ee >= 0) a32 += ea[(size_t)ee * ED + (lane & 31)];
            }
        }
        a32 += __shfl_xor(a32, 32);
        float zd = ax0 + ax1;
#pragma unroll
        for (int j = 0; j < ED; ++j)
            zd = fmaf(__shfl(a32, j), w[j], zd);
        zd = fmaf((float)(j1 - j0), ebl, zd);
        z[(size_t)n * D + lane] = zd;
    }
}

// ---------------- fallback C (tiny ws): atomic version ----------------

__global__ void __launch_bounds__(256) edge_scatter_fb(
    const float* __restrict__ x, const int* __restrict__ ei,
    const float* __restrict__ ea, const float* __restrict__ ew,
    const float* __restrict__ eb, float* __restrict__ agg, float* __restrict__ deg) {
    const int lane = threadIdx.x & 63;
    const int wid  = blockIdx.x * (blockDim.x >> 6) + (threadIdx.x >> 6);
    const int nw   = gridDim.x * (blockDim.x >> 6);
    float w[ED];
#pragma unroll
    for (int k = 0; k < ED; ++k) w[k] = ew[lane * ED + k];
    const float b = eb[lane];
    for (int e = wid; e < N_EDGES; e += nw) {
        const int r = ei[e];
        const int c = ei[N_EDGES + e];
        const float4* ea4 = (const float4*)(ea + (size_t)e * ED);
        float acc = b;
#pragma unroll
        for (int q = 0; q < ED / 4; ++q) {
            float4 v = ea4[q];
            acc = fmaf(v.x, w[4*q+0], acc); acc = fmaf(v.y, w[4*q+1], acc);
            acc = fmaf(v.z, w[4*q+2], acc); acc = fmaf(v.w, w[4*q+3], acc);
        }
        acc += x[(size_t)r * D + lane];
        atomicAdd(&agg[(size_t)c * D + lane], acc);
        if (lane == 0) atomicAdd(&deg[c], 1.0f);
    }
}

__global__ void __launch_bounds__(256) node_linear_fb(
    float* __restrict__ agg, const float* __restrict__ deg,
    const float* __restrict__ lw, const float* __restrict__ lb) {
    const int lane = threadIdx.x & 63;
    const int wid  = blockIdx.x * (blockDim.x >> 6) + (threadIdx.x >> 6);
    const int nw   = gridDim.x * (blockDim.x >> 6);
    float w[D];
#pragma unroll
    for (int k = 0; k < D; ++k) w[k] = lw[lane * D + k];
    const float b = lb[lane];
    for (int n = wid; n < N_NODES; n += nw) {
        const float inv = 1.0f / fmaxf(deg[n], 1.0f);
        const float4* a4 = (const float4*)(agg + (size_t)n * D);
        float dot = 0.0f;
#pragma unroll
        for (int q = 0; q < D / 4; ++q) {
            float4 v = a4[q];
            dot = fmaf(v.x, w[4*q+0], dot); dot = fmaf(v.y, w[4*q+1], dot);
            dot = fmaf(v.z, w[4*q+2], dot); dot = fmaf(v.w, w[4*q+3], dot);
        }
        agg[(size_t)n * D + lane] = fmaf(inv, dot, b);
    }
}

// ---------------- launch ----------------

extern "C" void kernel_launch(void* const* d_in, const int* in_sizes, int n_in,
                              void* d_out, int out_size, void* d_ws, size_t ws_size,
                              hipStream_t stream) {
    const float* x  = (const float*)d_in[0];
    const int*   ei = (const int*)d_in[1];     // [2][E]: rows then cols
    const float* ea = (const float*)d_in[2];
    const float* lw = (const float*)d_in[3];
    const float* lb = (const float*)d_in[4];
    const float* ew = (const float*)d_in[5];
    const float* eb = (const float*)d_in[6];
    const int* row = ei;
    const int* col = ei + N_EDGES;

    char* ws = (char*)d_ws;
    float* zout = (float*)d_out;

    // ---- A: permuted bf16 payload (needs ~86 MB) ----
    const size_t A_EAP  = 0;                                  // E*32 ushort + pad
    const size_t A_ROWP = (size_t)N_EDGES * ED * 2 + 64;      // 80,000,064
    const size_t A_CNT  = A_ROWP + (size_t)N_EDGES * 4;       // 85,000,064
    const size_t A_BASE = A_CNT + 400000;                     // 85,400,064
    const size_t A_BSUM = A_BASE + 400016;                    // 85,800,080
    const size_t A_BOFF = A_BSUM + 784;
    const size_t REQ_A  = A_BOFF + 784;

    // ---- B: R4 pipeline (needs ~10.8 MB) ----
    const size_t B_EREC = 0;
    const size_t B_CNT  = 10000000;
    const size_t B_BASE = 10400000;
    const size_t B_BSUM = 10800016;
    const size_t B_BOFF = 10800800;
    const size_t REQ_B  = 10801584;

    if (ws_size >= REQ_A) {
        ushort* eap  = (ushort*)(ws + A_EAP);
        int*    rowp = (int*)(ws + A_ROWP);
        int*    cnt  = (int*)(ws + A_CNT);
        int*    base = (int*)(ws + A_BASE);
        int*    bsum = (int*)(ws + A_BSUM);
        int*    boff = (int*)(ws + A_BOFF);

        hipMemsetAsync(cnt, 0, (size_t)N_NODES * sizeof(int), stream);
        hist_k        <<<1024, 256, 0, stream>>>(col, cnt);
        scan_local_k  <<<SCAN_NB, SCAN_BS, 0, stream>>>(cnt, base, bsum);
        scan_bsum_k   <<<1, 256, 0, stream>>>(bsum, boff);
        scan_add_k    <<<SCAN_NB, SCAN_BS, 0, stream>>>(base, boff, cnt /*cursor*/);
        scatter_perm_k<<<2048, 256, 0, stream>>>(row, col, cnt /*cursor*/, ea, rowp, eap);
        agg_k         <<<2048, 256, 0, stream>>>(x, base, rowp, eap, ew, eb, zout);
        out_k         <<<1024, 256, 0, stream>>>(zout, base, lw, lb);
    } else if (ws_size >= REQ_B) {
        int2* erec = (int2*)(ws + B_EREC);
        int*  cnt  = (int*)(ws + B_CNT);
        int*  base = (int*)(ws + B_BASE);
        int*  bsum = (int*)(ws + B_BSUM);
        int*  boff = (int*)(ws + B_BOFF);

        hipMemsetAsync(cnt, 0, (size_t)N_NODES * sizeof(int), stream);
        hist_k      <<<1024, 256, 0, stream>>>(col, cnt);
        scan_local_k<<<SCAN_NB, SCAN_BS, 0, stream>>>(cnt, base, bsum);
        scan_bsum_k <<<1, 256, 0, stream>>>(bsum, boff);
        scan_add_k  <<<SCAN_NB, SCAN_BS, 0, stream>>>(base, boff, cnt /*cursor*/);
        scatter_fb_k<<<1024, 256, 0, stream>>>(row, col, cnt /*cursor*/, erec);
        agg_fb_k    <<<2048, 256, 0, stream>>>(x, ea, base, erec, ew, eb, zout);
        out_k       <<<1024, 256, 0, stream>>>(zout, base, lw, lb);
    } else {
        float* deg = (float*)d_ws;
        hipMemsetAsync(zout, 0, (size_t)N_NODES * D * sizeof(float), stream);
        hipMemsetAsync(deg, 0, (size_t)N_NODES * sizeof(float), stream);
        edge_scatter_fb<<<2048, 256, 0, stream>>>(x, ei, ea, ew, eb, zout, deg);
        node_linear_fb <<<1024, 256, 0, stream>>>(zout, deg, lw, lb);
    }
}